// Round 1
// baseline (386.108 us; speedup 1.0000x reference)
//
#include <hip/hip_runtime.h>

typedef unsigned short u16;
using bf16x8 = __attribute__((ext_vector_type(8))) __bf16;
using f32x4  = __attribute__((ext_vector_type(4))) float;

#define GL_TO_LDS(gp, sp) \
  __builtin_amdgcn_global_load_lds((const __attribute__((address_space(1))) void*)(gp), \
                                   (__attribute__((address_space(3))) void*)(sp), 16, 0, 0)

__device__ __forceinline__ u16 f2bf(float f){
  unsigned u = __builtin_bit_cast(unsigned, f);
  u += 0x7fffu + ((u >> 16) & 1u);
  return (u16)(u >> 16);
}

constexpr int SB = 4, SL = 4096, SD = 1024;
constexpr int GM = SB * SL, GN = SD, GK = SD;      // 16384 x 1024 x 1024
constexpr int NCHUNK = 64, CH = SL / NCHUNK;       // 64 chunks of 64
constexpr float EPS_PHAZOR = 1e-5f;
constexpr float LOG2_SCALE = -9.965784284662087f;  // log2(0.001)

// ---------------- f32 -> bf16 conversion of x and the 4 weight matrices ----------------
__global__ __launch_bounds__(256) void k_convert(
    const float4* __restrict__ x4, const float4* __restrict__ wz4,
    const float4* __restrict__ wza4, const float4* __restrict__ wy4,
    const float4* __restrict__ wya4, u16* __restrict__ xb, u16* __restrict__ wb){
  int gid = blockIdx.x * 256 + threadIdx.x;   // each handles 8 floats
  const float4* src; u16* dst;
  if (gid < (GM * GK / 8)){
    src = x4 + (size_t)gid * 2; dst = xb + (size_t)gid * 8;
  } else {
    int g2 = gid - GM * GK / 8;
    int which = g2 >> 17, off = g2 & 0x1ffff;   // 131072 groups of 8 per 1024x1024 weight
    const float4* s4 = which == 0 ? wz4 : which == 1 ? wza4 : which == 2 ? wy4 : wya4;
    src = s4 + (size_t)off * 2; dst = wb + (size_t)which * (GK * GN) + (size_t)off * 8;
  }
  float4 a = src[0], b = src[1];
  u16 r[8] = {f2bf(a.x), f2bf(a.y), f2bf(a.z), f2bf(a.w),
              f2bf(b.x), f2bf(b.y), f2bf(b.z), f2bf(b.w)};
  *reinterpret_cast<uint4*>(dst) = *reinterpret_cast<const uint4*>(r);
}

// ---------------- fused dual GEMM: out = (A0@W0^T + b0) * silu(A1@W1^T + b1) ----------------
// m97-style: 128x128 tile, BK=32, 4 waves (2x2), each wave 64x64 via 4x4 frags of 16x16x32.
template<bool SAME_A>
__global__ __launch_bounds__(256, 2) void k_gemm_dual(
    const u16* __restrict__ A0, const u16* __restrict__ A1,
    const u16* __restrict__ W0, const u16* __restrict__ W1,
    const float* __restrict__ bias0, const float* __restrict__ bias1,
    float* __restrict__ out){
  __shared__ u16 sA0[128][32];
  __shared__ u16 sB0[128][32];
  __shared__ u16 sB1[128][32];
  __shared__ u16 sA1[SAME_A ? 4 : 128][32];

  const int tid  = threadIdx.x;
  const int wave = tid >> 6, lane = tid & 63;
  const int wm = wave >> 1, wn = wave & 1;
  const int lr = lane & 15, lg = lane >> 4;
  const int bm = blockIdx.y, bn = blockIdx.x;

  // staging geometry: 512 chunks of 16B per 128x32 tile; 2 chunks/thread
  const int r0 = tid >> 2, s0 = tid & 3;
  const int c1 = 256 + tid;
  const int r1 = c1 >> 2, s1 = c1 & 3;
  const int sp0 = (wave * 64) * 8;          // wave-uniform LDS element offsets
  const int sp1 = (256 + wave * 64) * 8;

  f32x4 acc0[4][4] = {};
  f32x4 acc1[4][4] = {};

  for (int k0 = 0; k0 < GK; k0 += 32){
    {
      const u16* g;
      g = A0 + (size_t)(bm * 128 + r0) * GK + k0 + s0 * 8; GL_TO_LDS(g, &sA0[0][0] + sp0);
      g = A0 + (size_t)(bm * 128 + r1) * GK + k0 + s1 * 8; GL_TO_LDS(g, &sA0[0][0] + sp1);
      g = W0 + (size_t)(bn * 128 + r0) * GK + k0 + s0 * 8; GL_TO_LDS(g, &sB0[0][0] + sp0);
      g = W0 + (size_t)(bn * 128 + r1) * GK + k0 + s1 * 8; GL_TO_LDS(g, &sB0[0][0] + sp1);
      g = W1 + (size_t)(bn * 128 + r0) * GK + k0 + s0 * 8; GL_TO_LDS(g, &sB1[0][0] + sp0);
      g = W1 + (size_t)(bn * 128 + r1) * GK + k0 + s1 * 8; GL_TO_LDS(g, &sB1[0][0] + sp1);
      if constexpr(!SAME_A){
        g = A1 + (size_t)(bm * 128 + r0) * GK + k0 + s0 * 8; GL_TO_LDS(g, &sA1[0][0] + sp0);
        g = A1 + (size_t)(bm * 128 + r1) * GK + k0 + s1 * 8; GL_TO_LDS(g, &sA1[0][0] + sp1);
      }
    }
    __syncthreads();

    bf16x8 a0f[4], b0f[4], b1f[4], a1f[4];
    #pragma unroll
    for (int f = 0; f < 4; f++){
      a0f[f] = *reinterpret_cast<const bf16x8*>(&sA0[wm * 64 + f * 16 + lr][lg * 8]);
      b0f[f] = *reinterpret_cast<const bf16x8*>(&sB0[wn * 64 + f * 16 + lr][lg * 8]);
      b1f[f] = *reinterpret_cast<const bf16x8*>(&sB1[wn * 64 + f * 16 + lr][lg * 8]);
      if constexpr(!SAME_A)
        a1f[f] = *reinterpret_cast<const bf16x8*>(&sA1[wm * 64 + f * 16 + lr][lg * 8]);
    }
    #pragma unroll
    for (int mf = 0; mf < 4; mf++){
      #pragma unroll
      for (int nf = 0; nf < 4; nf++){
        acc0[mf][nf] = __builtin_amdgcn_mfma_f32_16x16x32_bf16(a0f[mf], b0f[nf], acc0[mf][nf], 0, 0, 0);
        if constexpr(SAME_A)
          acc1[mf][nf] = __builtin_amdgcn_mfma_f32_16x16x32_bf16(a0f[mf], b1f[nf], acc1[mf][nf], 0, 0, 0);
        else
          acc1[mf][nf] = __builtin_amdgcn_mfma_f32_16x16x32_bf16(a1f[mf], b1f[nf], acc1[mf][nf], 0, 0, 0);
      }
    }
    __syncthreads();
  }

  // epilogue: C/D layout col = lane&15, row = (lane>>4)*4 + reg  [m89-verified]
  #pragma unroll
  for (int nf = 0; nf < 4; nf++){
    const int col = bn * 128 + wn * 64 + nf * 16 + lr;
    const float bb0 = bias0[col], bb1 = bias1[col];
    #pragma unroll
    for (int mf = 0; mf < 4; mf++){
      const int rowb = bm * 128 + wm * 64 + mf * 16 + lg * 4;
      f32x4 v0 = acc0[mf][nf], v1 = acc1[mf][nf];
      #pragma unroll
      for (int r = 0; r < 4; r++){
        float p0 = v0[r] + bb0, p1 = v1[r] + bb1;
        float sg = p1 / (1.f + __expf(-p1));
        out[(size_t)(rowb + r) * GN + col] = p0 * sg;
      }
    }
  }
}

// ---------------- chunked complex scan: h[l] = r*h[l-1] + z[l], h[-1] = last_conv ----------------
__global__ __launch_bounds__(256) void k_scan1(const float* __restrict__ z, float2* __restrict__ carry){
  const int d = blockIdx.x * 256 + threadIdx.x;
  const int c = blockIdx.y, b = blockIdx.z;
  const float sc = exp2f(LOG2_SCALE * ((float)d * (1.0f / 1023.0f)));
  float si, co; sincosf(sc, &si, &co);
  const float er = expf(EPS_PHAZOR);
  const float rre = er * co, rim = er * si;
  const float* zp = z + ((size_t)b * SL + (size_t)c * CH) * SD + d;
  float hre = 0.f, him = 0.f;
  #pragma unroll 8
  for (int i = 0; i < CH; i++){
    float zv = zp[i * SD];
    float nr = fmaf(rre, hre, fmaf(-rim, him, zv));
    him = fmaf(rre, him, rim * hre);
    hre = nr;
  }
  carry[(size_t)(b * NCHUNK + c) * SD + d] = make_float2(hre, him);
}

__global__ __launch_bounds__(256) void k_scan2(const float2* __restrict__ carry,
    const float* __restrict__ lcre, const float* __restrict__ lcim, float2* __restrict__ hin){
  const int idx = blockIdx.x * 256 + threadIdx.x;  // b*1024 + d
  const int b = idx >> 10, d = idx & 1023;
  const float sc = exp2f(LOG2_SCALE * ((float)d * (1.0f / 1023.0f)));
  float si, co; sincosf((float)CH * sc, &si, &co);
  const float eC = expf((float)CH * EPS_PHAZOR);
  const float Rre = eC * co, Rim = eC * si;
  float hre = lcre[d], him = lcim[d];
  for (int c = 0; c < NCHUNK; c++){
    const size_t o = (size_t)(b * NCHUNK + c) * SD + d;
    hin[o] = make_float2(hre, him);
    float2 cv = carry[o];
    float nr = fmaf(Rre, hre, fmaf(-Rim, him, cv.x));
    him = fmaf(Rre, him, fmaf(Rim, hre, cv.y));
    hre = nr;
  }
}

__global__ __launch_bounds__(256) void k_scan3(float* __restrict__ zh, const float2* __restrict__ hin){
  const int d = blockIdx.x * 256 + threadIdx.x;
  const int c = blockIdx.y, b = blockIdx.z;
  const float sc = exp2f(LOG2_SCALE * ((float)d * (1.0f / 1023.0f)));
  float si, co; sincosf(sc, &si, &co);
  const float er = expf(EPS_PHAZOR);
  const float rre = er * co, rim = er * si;
  float2 h0 = hin[(size_t)(b * NCHUNK + c) * SD + d];
  float hre = h0.x, him = h0.y;
  float* zp = zh + ((size_t)b * SL + (size_t)c * CH) * SD + d;
  #pragma unroll 8
  for (int i = 0; i < CH; i++){
    float zv = zp[i * SD];
    float nr = fmaf(rre, hre, fmaf(-rim, him, zv));
    him = fmaf(rre, him, rim * hre);
    hre = nr;
    zp[i * SD] = hre;   // in-place: z -> Re(h)
  }
}

// ---------------- RMSNorm row kernel -> bf16 normed ----------------
__global__ __launch_bounds__(256) void k_rmsnorm(const float* __restrict__ h,
    const float* __restrict__ nw, u16* __restrict__ outb){
  const int row = blockIdx.x, tid = threadIdx.x;
  const float4 v = reinterpret_cast<const float4*>(h + (size_t)row * SD)[tid];
  float ss = v.x * v.x + v.y * v.y + v.z * v.z + v.w * v.w;
  #pragma unroll
  for (int o = 32; o; o >>= 1) ss += __shfl_down(ss, o, 64);
  __shared__ float red[5];
  const int lane = tid & 63, wid = tid >> 6;
  if (lane == 0) red[wid] = ss;
  __syncthreads();
  if (tid == 0) red[4] = rsqrtf((red[0] + red[1] + red[2] + red[3]) * (1.0f / (float)SD) + 1e-6f);
  __syncthreads();
  const float inv = red[4];
  const float4 w = reinterpret_cast<const float4*>(nw)[tid];
  u16 r[4] = { f2bf(v.x * inv * w.x), f2bf(v.y * inv * w.y),
               f2bf(v.z * inv * w.z), f2bf(v.w * inv * w.w) };
  reinterpret_cast<ushort4*>(outb + (size_t)row * SD)[tid] = *reinterpret_cast<const ushort4*>(r);
}

// ---------------- launch ----------------
extern "C" void kernel_launch(void* const* d_in, const int* in_sizes, int n_in,
                              void* d_out, int out_size, void* d_ws, size_t ws_size,
                              hipStream_t stream){
  const float* x    = (const float*)d_in[0];
  const float* Wz   = (const float*)d_in[1];
  const float* bz   = (const float*)d_in[2];
  const float* Wza  = (const float*)d_in[3];
  const float* bza  = (const float*)d_in[4];
  const float* Wy   = (const float*)d_in[5];
  const float* by   = (const float*)d_in[6];
  const float* Wya  = (const float*)d_in[7];
  const float* bya  = (const float*)d_in[8];
  const float* nw   = (const float*)d_in[9];
  const float* lcre = (const float*)d_in[10];
  const float* lcim = (const float*)d_in[11];

  char* ws = (char*)d_ws;
  // workspace layout (136 MB total):
  //   [0,32M)   xb   : x in bf16
  //   [32M,40M) wb   : Wz,Wza,Wy,Wya in bf16 (contiguous, 2MB each)
  //   [40M,72M) normedb (bf16) -- overlaid with carry[40M,42M) + hin[42M,44M) (dead before rmsnorm)
  //   [72M,136M) zbuf : z (f32), overwritten in-place with Re(h)
  u16*    xb      = (u16*)(ws);
  u16*    wb      = (u16*)(ws + (32ull << 20));
  u16*    normedb = (u16*)(ws + (40ull << 20));
  float2* carry   = (float2*)(ws + (40ull << 20));
  float2* hin     = (float2*)(ws + (42ull << 20));
  float*  zbuf    = (float*)(ws + (72ull << 20));
  float*  y       = (float*)d_out;

  k_convert<<<10240, 256, 0, stream>>>((const float4*)x, (const float4*)Wz, (const float4*)Wza,
                                       (const float4*)Wy, (const float4*)Wya, xb, wb);
  k_gemm_dual<true ><<<dim3(GN / 128, GM / 128), 256, 0, stream>>>(
      xb, xb, wb, wb + (size_t)GK * GN, bz, bza, zbuf);
  k_scan1<<<dim3(SD / 256, NCHUNK, SB), 256, 0, stream>>>(zbuf, carry);
  k_scan2<<<(SB * SD) / 256, 256, 0, stream>>>(carry, lcre, lcim, hin);
  k_scan3<<<dim3(SD / 256, NCHUNK, SB), 256, 0, stream>>>(zbuf, hin);
  k_rmsnorm<<<GM, 256, 0, stream>>>(zbuf, nw, normedb);
  k_gemm_dual<false><<<dim3(GN / 128, GM / 128), 256, 0, stream>>>(
      normedb, xb, wb + 2ull * GK * GN, wb + 3ull * GK * GN, by, bya, y);
}